// Round 3
// baseline (269.681 us; speedup 1.0000x reference)
//
#include <hip/hip_runtime.h>
#include <hip/hip_bf16.h>

#define B_SZ 8192
#define S_DIM 512
#define H_DIM 1024
#define E_DIM 256
#define A_DIM 32

typedef __attribute__((ext_vector_type(4))) float f32x4;
typedef __attribute__((ext_vector_type(8))) __bf16 bf16x8;

using as1_void = __attribute__((address_space(1))) void;
using as3_void = __attribute__((address_space(3))) void;

#define WAITV(N) asm volatile("s_waitcnt vmcnt(" #N ")" ::: "memory")
#define LGKM0 asm volatile("s_waitcnt lgkmcnt(0)" ::: "memory")

__device__ __forceinline__ unsigned short f2bfu(float f) {
  unsigned u = __builtin_bit_cast(unsigned, f);
  unsigned r = (u + 0x7FFFu + ((u >> 16) & 1u)) >> 16;
  return (unsigned short)r;
}
__device__ __forceinline__ float bf2f(unsigned short x) {
  unsigned u = ((unsigned)x) << 16;
  return __builtin_bit_cast(float, u);
}

// elementwise f32 -> bf16 (n multiple of 4)
__global__ void conv_kernel(const float* __restrict__ in, unsigned short* __restrict__ out, int n) {
  int i = blockIdx.x * blockDim.x + threadIdx.x;
  int idx = i * 4;
  if (idx >= n) return;
  const float4 v = *(const float4*)(in + idx);
  ushort4 o;
  o.x = f2bfu(v.x); o.y = f2bfu(v.y); o.z = f2bfu(v.z); o.w = f2bfu(v.w);
  *(ushort4*)(out + idx) = o;
}

// transpose+convert: in [R][C] f32 -> out [C][R] bf16. R,C multiples of 32.
__global__ void tconv_kernel(const float* __restrict__ in, unsigned short* __restrict__ out,
                             int R, int C) {
  __shared__ float t[32][33];
  int tx = threadIdx.x, ty = threadIdx.y;
  int c0 = blockIdx.x * 32, r0 = blockIdx.y * 32;
#pragma unroll
  for (int i = 0; i < 4; ++i) {
    int r = r0 + ty + i * 8;
    t[ty + i * 8][tx] = in[(size_t)r * C + c0 + tx];
  }
  __syncthreads();
#pragma unroll
  for (int i = 0; i < 4; ++i) {
    int c = c0 + ty + i * 8;
    out[(size_t)c * R + r0 + tx] = f2bfu(t[tx][ty + i * 8]);
  }
}

// ---------------- 128x128 2-phase GEMM (m97 structure) for small/medium GEMMs -------------
template <int ACT>
__global__ void gemm_bt(const unsigned short* __restrict__ A,
                        const unsigned short* __restrict__ BT,
                        const float* __restrict__ bias, void* __restrict__ Cp,
                        int M, int N, int K) {
  __shared__ unsigned short As[128 * 64];
  __shared__ unsigned short Bs[128 * 64];
  const int tid = threadIdx.x;
  const int w = tid >> 6, l = tid & 63;
  const int wr = w >> 1, wc = w & 1;
  const int row0 = blockIdx.y * 128, col0 = blockIdx.x * 128;
  f32x4 acc[4][4] = {};
  for (int k0 = 0; k0 < K; k0 += 64) {
    __syncthreads();
#pragma unroll
    for (int i = 0; i < 4; ++i) {
      int cbase = i * 256 + w * 64;
      int c = cbase + l;
      int r = c >> 3, kc = c & 7;
      const unsigned short* src = A + (size_t)(row0 + r) * K + (k0 + kc * 8);
      __builtin_amdgcn_global_load_lds((const as1_void*)src, (as3_void*)&As[cbase * 8], 16, 0, 0);
    }
#pragma unroll
    for (int i = 0; i < 4; ++i) {
      int cbase = i * 256 + w * 64;
      int c = cbase + l;
      int r = c >> 3, kc = c & 7;
      const unsigned short* src = BT + (size_t)(col0 + r) * K + (k0 + kc * 8);
      __builtin_amdgcn_global_load_lds((const as1_void*)src, (as3_void*)&Bs[cbase * 8], 16, 0, 0);
    }
    __syncthreads();
#pragma unroll
    for (int kk = 0; kk < 2; ++kk) {
      bf16x8 af[4], bfr[4];
#pragma unroll
      for (int i = 0; i < 4; ++i)
        af[i] = *(const bf16x8*)&As[(wr * 64 + i * 16 + (l & 15)) * 64 + kk * 32 + (l >> 4) * 8];
#pragma unroll
      for (int j = 0; j < 4; ++j)
        bfr[j] = *(const bf16x8*)&Bs[(wc * 64 + j * 16 + (l & 15)) * 64 + kk * 32 + (l >> 4) * 8];
#pragma unroll
      for (int i = 0; i < 4; ++i)
#pragma unroll
        for (int j = 0; j < 4; ++j)
          acc[i][j] = __builtin_amdgcn_mfma_f32_16x16x32_bf16(af[i], bfr[j], acc[i][j], 0, 0, 0);
    }
  }
#pragma unroll
  for (int i = 0; i < 4; ++i)
#pragma unroll
    for (int j = 0; j < 4; ++j)
#pragma unroll
      for (int t = 0; t < 4; ++t) {
        int r = row0 + wr * 64 + i * 16 + (l >> 4) * 4 + t;
        int c = col0 + wc * 64 + j * 16 + (l & 15);
        float v = acc[i][j][t] + bias[c];
        if (ACT == 1) v = fmaxf(v, 0.0f);
        if (ACT == 2) v = fabsf(v);
        if (ACT == 0)
          ((float*)Cp)[(size_t)r * N + c] = v;
        else
          ((unsigned short*)Cp)[(size_t)r * N + c] = f2bfu(v);
      }
}

// ---------------- 256x256 8-phase deep-pipelined GEMM (T2+T3+T4+T5, m201 schedule) -------
// 8 phases / 2 K-tiles per iteration. Tile 2i -> buf0, 2i+1 -> buf1 (fixed parity).
// Quadrant (snake) order per K-tile: q(0,0) q(1,0) q(1,1) q(0,1).
// LDS read windows (per K-tile): B0@p1, A1@p2, B1@p3, A0@p1+p4.
// Stage slots: p1: buf1.A0<-t(2i+1); p2: buf0.B0<-t(2i+2); p3: buf0.A1; p4: buf0.B1;
//              p5: buf0.A0; p6: buf1.B0<-t(2i+3); p7: buf1.A1; p8: buf1.B1.
// Waits: vmcnt(4) at p4/p8 only (2 half-tiles in flight); last iter p4 -> vmcnt(0).
// Two s_barrier per phase; stage-issue always after the trailing barrier of the last
// phase that ds_reads the target region (verified slot-by-slot).
template <int ACT>
__global__ __launch_bounds__(512, 2) void gemm256_bt(
    const unsigned short* __restrict__ A, const unsigned short* __restrict__ BT,
    const float* __restrict__ bias, void* __restrict__ Cp, int M, int N, int K) {
  __shared__ __align__(16) char smem[131072];  // A: [0,64K) B: [64K,128K); 2 buf x 2 half x 16KB
  const int tid = threadIdx.x;
  const int w = tid >> 6, l = tid & 63;
  const int wrow = w >> 2, wcol = w & 3;
  const int row0 = blockIdx.y * 256, col0 = blockIdx.x * 256;
  const int NP = K >> 7;  // iterations, 2 K-tiles each; requires K%128==0, NP>=1

  bf16x8 af[8];   // A-frags for current A-half: [i][kk]
  bf16x8 bfr[4];  // B-frags for current B-half: [j][kk]
  f32x4 acc[2][2][4][2] = {};

  auto stage = [&](int mat, int h, int t, int buf) {
    const unsigned short* base = mat ? BT : A;
    const int rbase = (mat ? col0 : row0) + h * 128;
    const int k0 = t * 64;
    char* region = smem + mat * 65536 + buf * 32768 + h * 16384;
#pragma unroll
    for (int j = 0; j < 2; ++j) {
      const int c = j * 512 + w * 64 + l;  // chunk id 0..1023
      const int r = c >> 3, kc = c & 7;
      const unsigned short* src =
          base + (size_t)(rbase + r) * K + (k0 + ((kc ^ (r & 7)) << 3));
      __builtin_amdgcn_global_load_lds((const as1_void*)src,
                                       (as3_void*)(region + (j * 512 + w * 64) * 16), 16, 0, 0);
    }
  };
  auto lda = [&](int qa, int buf) {
    const char* region = smem + buf * 32768 + qa * 16384;
#pragma unroll
    for (int i = 0; i < 4; ++i) {
      const int r = wrow * 64 + i * 16 + (l & 15);
#pragma unroll
      for (int kk = 0; kk < 2; ++kk) {
        const int kc = kk * 4 + (l >> 4);
        af[i * 2 + kk] = *(const bf16x8*)(region + r * 128 + ((kc ^ (r & 7)) << 4));
      }
    }
  };
  auto ldb = [&](int qb, int buf) {
    const char* region = smem + 65536 + buf * 32768 + qb * 16384;
#pragma unroll
    for (int j = 0; j < 2; ++j) {
      const int r = wcol * 32 + j * 16 + (l & 15);
#pragma unroll
      for (int kk = 0; kk < 2; ++kk) {
        const int kc = kk * 4 + (l >> 4);
        bfr[j * 2 + kk] = *(const bf16x8*)(region + r * 128 + ((kc ^ (r & 7)) << 4));
      }
    }
  };
  auto mf = [&](f32x4 (&ac)[4][2]) {
    __builtin_amdgcn_s_setprio(1);
#pragma unroll
    for (int i = 0; i < 4; ++i)
#pragma unroll
      for (int j = 0; j < 2; ++j)
#pragma unroll
        for (int kk = 0; kk < 2; ++kk)
          ac[i][j] = __builtin_amdgcn_mfma_f32_16x16x32_bf16(af[i * 2 + kk], bfr[j * 2 + kk],
                                                             ac[i][j], 0, 0, 0);
    __builtin_amdgcn_s_setprio(0);
  };
  auto bar = [&]() {
    asm volatile("" ::: "memory");
    __builtin_amdgcn_s_barrier();
    asm volatile("" ::: "memory");
  };

  // prologue: tile0 -> buf0, tile1 -> buf1 (16 loads), drain tile0's 8 before ph1
  stage(0, 0, 0, 0); stage(1, 0, 0, 0); stage(0, 1, 0, 0); stage(1, 1, 0, 0);
  stage(1, 0, 1, 1); stage(0, 1, 1, 1); stage(1, 1, 1, 1); stage(0, 0, 1, 1);
  WAITV(8);
  bar();

  for (int i = 0; i < NP; ++i) {
    const bool stg = (i < NP - 1);
    const int t2 = 2 * i + 2, t3 = 2 * i + 3;
    // p1: q(0,0) on buf0
    lda(0, 0); ldb(0, 0);
    if (i > 0) stage(0, 0, 2 * i + 1, 1);
    bar(); LGKM0; mf(acc[0][0]); bar();
    // p2: q(1,0)
    lda(1, 0);
    if (stg) stage(1, 0, t2, 0);
    bar(); LGKM0; mf(acc[1][0]); bar();
    // p3: q(1,1)
    ldb(1, 0);
    if (stg) stage(0, 1, t2, 0);
    bar(); LGKM0; mf(acc[1][1]); bar();
    // p4: q(0,1) — K-tile wait
    lda(0, 0);
    if (stg) { stage(1, 1, t2, 0); WAITV(4); } else { WAITV(0); }
    bar(); LGKM0; mf(acc[0][1]); bar();
    // p5: q(0,0) on buf1
    lda(0, 1); ldb(0, 1);
    if (stg) stage(0, 0, t2, 0);
    bar(); LGKM0; mf(acc[0][0]); bar();
    // p6: q(1,0)
    lda(1, 1);
    if (stg) stage(1, 0, t3, 1);
    bar(); LGKM0; mf(acc[1][0]); bar();
    // p7: q(1,1)
    ldb(1, 1);
    if (stg) stage(0, 1, t3, 1);
    bar(); LGKM0; mf(acc[1][1]); bar();
    // p8: q(0,1) — K-tile wait
    lda(0, 1);
    if (stg) { stage(1, 1, t3, 1); WAITV(4); }
    bar(); LGKM0; mf(acc[0][1]); bar();
  }

#pragma unroll
  for (int qa = 0; qa < 2; ++qa)
#pragma unroll
    for (int qb = 0; qb < 2; ++qb)
#pragma unroll
      for (int i = 0; i < 4; ++i)
#pragma unroll
        for (int j = 0; j < 2; ++j)
#pragma unroll
          for (int tt = 0; tt < 4; ++tt) {
            const int r = row0 + qa * 128 + wrow * 64 + i * 16 + (l >> 4) * 4 + tt;
            const int cc = col0 + qb * 128 + wcol * 32 + j * 16 + (l & 15);
            float v = acc[qa][qb][i][j][tt] + bias[cc];
            if (ACT == 1) v = fmaxf(v, 0.0f);
            if (ACT == 2) v = fabsf(v);
            if (ACT == 0)
              ((float*)Cp)[(size_t)r * N + cc] = v;
            else
              ((unsigned short*)Cp)[(size_t)r * N + cc] = f2bfu(v);
          }
}

// Per-row fusion: hidden = elu(sum_a q[a]*|w1[b,a,:]| + b1), q_tot = hidden.wf + vh.vw2 + vb2
__global__ void final_kernel(const float* __restrict__ qs, const unsigned short* __restrict__ w1c,
                             const float* __restrict__ b1, const unsigned short* __restrict__ wf,
                             const unsigned short* __restrict__ vh, const float* __restrict__ vw2,
                             const float* __restrict__ vb2, float* __restrict__ out, int row0) {
  const int tid = threadIdx.x;               // e in [0,256)
  const int b = row0 + blockIdx.x;
  const unsigned short* wrow = w1c + (size_t)blockIdx.x * (A_DIM * E_DIM);
  const float* qrow = qs + (size_t)b * A_DIM;
  float acc = b1[(size_t)b * E_DIM + tid];
#pragma unroll 8
  for (int a = 0; a < A_DIM; ++a)
    acc = fmaf(qrow[a], bf2f(wrow[a * E_DIM + tid]), acc);
  float hidden = acc > 0.0f ? acc : (expf(acc) - 1.0f);  // elu, alpha=1
  float s = hidden * bf2f(wf[(size_t)b * E_DIM + tid]) +
            bf2f(vh[(size_t)b * E_DIM + tid]) * vw2[tid];
  __shared__ float red[4];
#pragma unroll
  for (int o = 32; o > 0; o >>= 1) s += __shfl_down(s, o, 64);
  if ((tid & 63) == 0) red[tid >> 6] = s;
  __syncthreads();
  if (tid == 0) out[b] = red[0] + red[1] + red[2] + red[3] + vb2[0];
}

extern "C" void kernel_launch(void* const* d_in, const int* in_sizes, int n_in,
                              void* d_out, int out_size, void* d_ws, size_t ws_size,
                              hipStream_t stream) {
  const float* agent_qs = (const float*)d_in[0];
  const float* states = (const float*)d_in[1];
  const float* hw1_w1 = (const float*)d_in[2];
  const float* hw1_b1 = (const float*)d_in[3];
  const float* hw1_w2 = (const float*)d_in[4];
  const float* hw1_b2 = (const float*)d_in[5];
  const float* hb1_w = (const float*)d_in[6];
  const float* hb1_b = (const float*)d_in[7];
  const float* hwf_w1 = (const float*)d_in[8];
  const float* hwf_b1 = (const float*)d_in[9];
  const float* hwf_w2 = (const float*)d_in[10];
  const float* hwf_b2 = (const float*)d_in[11];
  const float* v_w1 = (const float*)d_in[12];
  const float* v_b1 = (const float*)d_in[13];
  const float* v_w2 = (const float*)d_in[14];
  const float* v_b2 = (const float*)d_in[15];
  float* out = (float*)d_out;

  size_t off = 0;
  char* ws = (char*)d_ws;
  auto carve = [&](size_t bytes) -> void* {
    void* p = ws + off;
    off = (off + bytes + 255) & ~(size_t)255;
    return p;
  };
  unsigned short* st_bf = (unsigned short*)carve((size_t)B_SZ * S_DIM * 2);
  unsigned short* w11T = (unsigned short*)carve((size_t)H_DIM * S_DIM * 2);
  unsigned short* w12T = (unsigned short*)carve((size_t)8192 * H_DIM * 2);
  unsigned short* wb1T = (unsigned short*)carve((size_t)E_DIM * S_DIM * 2);
  unsigned short* wf1T = (unsigned short*)carve((size_t)H_DIM * S_DIM * 2);
  unsigned short* wf2T = (unsigned short*)carve((size_t)E_DIM * H_DIM * 2);
  unsigned short* wv1T = (unsigned short*)carve((size_t)E_DIM * S_DIM * 2);
  unsigned short* h1 = (unsigned short*)carve((size_t)B_SZ * H_DIM * 2);
  unsigned short* hfb = (unsigned short*)carve((size_t)B_SZ * H_DIM * 2);
  float* b1f = (float*)carve((size_t)B_SZ * E_DIM * 4);
  unsigned short* wfb = (unsigned short*)carve((size_t)B_SZ * E_DIM * 2);
  unsigned short* vhb = (unsigned short*)carve((size_t)B_SZ * E_DIM * 2);
  size_t rem = (ws_size > off) ? ws_size - off : 0;
  int chunk = (int)(rem / ((size_t)8192 * 2));
  chunk &= ~255;
  if (chunk < 256) chunk = 256;
  if (chunk > B_SZ) chunk = B_SZ;
  unsigned short* w1c = (unsigned short*)(ws + off);

  // dtype converts (+ weight transposes to B^T layout)
  conv_kernel<<<(B_SZ * S_DIM / 4 + 255) / 256, 256, 0, stream>>>(states, st_bf, B_SZ * S_DIM);
  dim3 tb(32, 8);
  tconv_kernel<<<dim3(H_DIM / 32, S_DIM / 32), tb, 0, stream>>>(hw1_w1, w11T, S_DIM, H_DIM);
  tconv_kernel<<<dim3(8192 / 32, H_DIM / 32), tb, 0, stream>>>(hw1_w2, w12T, H_DIM, 8192);
  tconv_kernel<<<dim3(E_DIM / 32, S_DIM / 32), tb, 0, stream>>>(hb1_w, wb1T, S_DIM, E_DIM);
  tconv_kernel<<<dim3(H_DIM / 32, S_DIM / 32), tb, 0, stream>>>(hwf_w1, wf1T, S_DIM, H_DIM);
  tconv_kernel<<<dim3(E_DIM / 32, H_DIM / 32), tb, 0, stream>>>(hwf_w2, wf2T, H_DIM, E_DIM);
  tconv_kernel<<<dim3(E_DIM / 32, S_DIM / 32), tb, 0, stream>>>(v_w1, wv1T, S_DIM, E_DIM);

  // small/medium GEMMs (128-tile 2-phase structure)
  gemm_bt<1><<<dim3(H_DIM / 128, B_SZ / 128), 256, 0, stream>>>(st_bf, w11T, hw1_b1, h1, B_SZ, H_DIM, S_DIM);
  gemm_bt<1><<<dim3(H_DIM / 128, B_SZ / 128), 256, 0, stream>>>(st_bf, wf1T, hwf_b1, hfb, B_SZ, H_DIM, S_DIM);
  gemm_bt<0><<<dim3(E_DIM / 128, B_SZ / 128), 256, 0, stream>>>(st_bf, wb1T, hb1_b, b1f, B_SZ, E_DIM, S_DIM);
  gemm_bt<1><<<dim3(E_DIM / 128, B_SZ / 128), 256, 0, stream>>>(st_bf, wv1T, v_b1, vhb, B_SZ, E_DIM, S_DIM);
  gemm_bt<2><<<dim3(E_DIM / 128, B_SZ / 128), 256, 0, stream>>>(hfb, wf2T, hwf_b2, wfb, B_SZ, E_DIM, H_DIM);

  // big GEMM (w1) on the 256-tile 8-phase pipeline, in row-chunks + fused epilogue
  for (int row0 = 0; row0 < B_SZ; row0 += chunk) {
    int cm = chunk;
    if (row0 + cm > B_SZ) cm = B_SZ - row0;
    gemm256_bt<2><<<dim3(8192 / 256, cm / 256), 512, 0, stream>>>(
        h1 + (size_t)row0 * H_DIM, w12T, hw1_b2, w1c, cm, 8192, H_DIM);
    final_kernel<<<cm, 256, 0, stream>>>(agent_qs, w1c, b1f, wfb, vhb, v_w2, v_b2, out, row0);
  }
}

// Round 4
// 256.019 us; speedup vs baseline: 1.0534x; 1.0534x over previous
//
#include <hip/hip_runtime.h>
#include <hip/hip_bf16.h>

#define B_SZ 8192
#define S_DIM 512
#define H_DIM 1024
#define E_DIM 256
#define A_DIM 32

typedef __attribute__((ext_vector_type(4))) float f32x4;
typedef __attribute__((ext_vector_type(8))) __bf16 bf16x8;

using as1_void = __attribute__((address_space(1))) void;
using as3_void = __attribute__((address_space(3))) void;

#define WAITV(N) asm volatile("s_waitcnt vmcnt(" #N ")" ::: "memory")

__device__ __forceinline__ unsigned short f2bfu(float f) {
  unsigned u = __builtin_bit_cast(unsigned, f);
  unsigned r = (u + 0x7FFFu + ((u >> 16) & 1u)) >> 16;
  return (unsigned short)r;
}
__device__ __forceinline__ float bf2f(unsigned short x) {
  unsigned u = ((unsigned)x) << 16;
  return __builtin_bit_cast(float, u);
}

// elementwise f32 -> bf16 (n multiple of 4)
__global__ void conv_kernel(const float* __restrict__ in, unsigned short* __restrict__ out, int n) {
  int i = blockIdx.x * blockDim.x + threadIdx.x;
  int idx = i * 4;
  if (idx >= n) return;
  const float4 v = *(const float4*)(in + idx);
  ushort4 o;
  o.x = f2bfu(v.x); o.y = f2bfu(v.y); o.z = f2bfu(v.z); o.w = f2bfu(v.w);
  *(ushort4*)(out + idx) = o;
}

// transpose+convert: in [R][C] f32 -> out [C][R] bf16. R,C multiples of 32.
__global__ void tconv_kernel(const float* __restrict__ in, unsigned short* __restrict__ out,
                             int R, int C) {
  __shared__ float t[32][33];
  int tx = threadIdx.x, ty = threadIdx.y;
  int c0 = blockIdx.x * 32, r0 = blockIdx.y * 32;
#pragma unroll
  for (int i = 0; i < 4; ++i) {
    int r = r0 + ty + i * 8;
    t[ty + i * 8][tx] = in[(size_t)r * C + c0 + tx];
  }
  __syncthreads();
#pragma unroll
  for (int i = 0; i < 4; ++i) {
    int c = c0 + ty + i * 8;
    out[(size_t)c * R + r0 + tx] = f2bfu(t[tx][ty + i * 8]);
  }
}

// ---------------- 128x128 2-phase GEMM (m97 structure) for small/medium GEMMs -------------
template <int ACT>
__global__ void gemm_bt(const unsigned short* __restrict__ A,
                        const unsigned short* __restrict__ BT,
                        const float* __restrict__ bias, void* __restrict__ Cp,
                        int M, int N, int K) {
  __shared__ unsigned short As[128 * 64];
  __shared__ unsigned short Bs[128 * 64];
  const int tid = threadIdx.x;
  const int w = tid >> 6, l = tid & 63;
  const int wr = w >> 1, wc = w & 1;
  const int row0 = blockIdx.y * 128, col0 = blockIdx.x * 128;
  f32x4 acc[4][4] = {};
  for (int k0 = 0; k0 < K; k0 += 64) {
    __syncthreads();
#pragma unroll
    for (int i = 0; i < 4; ++i) {
      int cbase = i * 256 + w * 64;
      int c = cbase + l;
      int r = c >> 3, kc = c & 7;
      const unsigned short* src = A + (size_t)(row0 + r) * K + (k0 + kc * 8);
      __builtin_amdgcn_global_load_lds((const as1_void*)src, (as3_void*)&As[cbase * 8], 16, 0, 0);
    }
#pragma unroll
    for (int i = 0; i < 4; ++i) {
      int cbase = i * 256 + w * 64;
      int c = cbase + l;
      int r = c >> 3, kc = c & 7;
      const unsigned short* src = BT + (size_t)(col0 + r) * K + (k0 + kc * 8);
      __builtin_amdgcn_global_load_lds((const as1_void*)src, (as3_void*)&Bs[cbase * 8], 16, 0, 0);
    }
    __syncthreads();
#pragma unroll
    for (int kk = 0; kk < 2; ++kk) {
      bf16x8 af[4], bfr[4];
#pragma unroll
      for (int i = 0; i < 4; ++i)
        af[i] = *(const bf16x8*)&As[(wr * 64 + i * 16 + (l & 15)) * 64 + kk * 32 + (l >> 4) * 8];
#pragma unroll
      for (int j = 0; j < 4; ++j)
        bfr[j] = *(const bf16x8*)&Bs[(wc * 64 + j * 16 + (l & 15)) * 64 + kk * 32 + (l >> 4) * 8];
#pragma unroll
      for (int i = 0; i < 4; ++i)
#pragma unroll
        for (int j = 0; j < 4; ++j)
          acc[i][j] = __builtin_amdgcn_mfma_f32_16x16x32_bf16(af[i], bfr[j], acc[i][j], 0, 0, 0);
    }
  }
#pragma unroll
  for (int i = 0; i < 4; ++i)
#pragma unroll
    for (int j = 0; j < 4; ++j)
#pragma unroll
      for (int t = 0; t < 4; ++t) {
        int r = row0 + wr * 64 + i * 16 + (l >> 4) * 4 + t;
        int c = col0 + wc * 64 + j * 16 + (l & 15);
        float v = acc[i][j][t] + bias[c];
        if (ACT == 1) v = fmaxf(v, 0.0f);
        if (ACT == 2) v = fabsf(v);
        if (ACT == 0)
          ((float*)Cp)[(size_t)r * N + c] = v;
        else
          ((unsigned short*)Cp)[(size_t)r * N + c] = f2bfu(v);
      }
}

// ---------------- 256x256 8-phase pipelined GEMM: 1 barrier/phase, counted vmcnt ---------
// 8 phases / 2 K-tiles per iteration; tile 2i -> buf0, 2i+1 -> buf1.
// Quadrant (snake) order per K-tile: q(0,0) q(1,0) q(1,1) q(0,1).
// LDS read windows (per K-tile): B0@p1, A1@p2, B1@p3, A0@p1+p4.
// Stage slots: p1: buf1.A0<-t(2i+1) [i>0]; p2..p5: buf0.{B0,A1,B1,A0}<-t(2i+2);
//              p6..p8: buf1.{B0,A1,B1}<-t(2i+3).
// Waits: vmcnt(4) at p4/p8 only; last iteration p4 -> vmcnt(0).
// Phase shape: [ds_read frags][stage-issue][wait?][s_barrier][setprio MFMA] — compiler
// manages lgkmcnt between ds_read and MFMA (fine-grained).
template <int ACT>
__global__ __launch_bounds__(512, 2) void gemm256_bt(
    const unsigned short* __restrict__ A, const unsigned short* __restrict__ BT,
    const float* __restrict__ bias, void* __restrict__ Cp, int M, int N, int K) {
  __shared__ __align__(16) char smem[131072];  // A: [0,64K) B: [64K,128K); 2 buf x 2 half x 16KB
  const int tid = threadIdx.x;
  const int w = tid >> 6, l = tid & 63;
  const int wrow = w >> 2, wcol = w & 3;
  const int row0 = blockIdx.y * 256, col0 = blockIdx.x * 256;
  const int NP = K >> 7;  // iterations, 2 K-tiles each; requires K%128==0, NP>=2

  bf16x8 af[8];   // A-frags for current A-half: [i][kk]
  bf16x8 bfr[4];  // B-frags for current B-half: [j][kk]
  f32x4 acc[2][2][4][2] = {};

  auto stage = [&](int mat, int h, int t, int buf) {
    const unsigned short* base = mat ? BT : A;
    const int rbase = (mat ? col0 : row0) + h * 128;
    const int k0 = t * 64;
    char* region = smem + mat * 65536 + buf * 32768 + h * 16384;
#pragma unroll
    for (int j = 0; j < 2; ++j) {
      const int c = j * 512 + w * 64 + l;  // chunk id 0..1023
      const int r = c >> 3, kc = c & 7;
      const unsigned short* src =
          base + (size_t)(rbase + r) * K + (k0 + ((kc ^ (r & 7)) << 3));
      __builtin_amdgcn_global_load_lds((const as1_void*)src,
                                       (as3_void*)(region + (j * 512 + w * 64) * 16), 16, 0, 0);
    }
  };
  auto lda = [&](int qa, int buf) {
    const char* region = smem + buf * 32768 + qa * 16384;
#pragma unroll
    for (int i = 0; i < 4; ++i) {
      const int r = wrow * 64 + i * 16 + (l & 15);
#pragma unroll
      for (int kk = 0; kk < 2; ++kk) {
        const int kc = kk * 4 + (l >> 4);
        af[i * 2 + kk] = *(const bf16x8*)(region + r * 128 + ((kc ^ (r & 7)) << 4));
      }
    }
  };
  auto ldb = [&](int qb, int buf) {
    const char* region = smem + 65536 + buf * 32768 + qb * 16384;
#pragma unroll
    for (int j = 0; j < 2; ++j) {
      const int r = wcol * 32 + j * 16 + (l & 15);
#pragma unroll
      for (int kk = 0; kk < 2; ++kk) {
        const int kc = kk * 4 + (l >> 4);
        bfr[j * 2 + kk] = *(const bf16x8*)(region + r * 128 + ((kc ^ (r & 7)) << 4));
      }
    }
  };
  auto mf = [&](f32x4 (&ac)[4][2]) {
    __builtin_amdgcn_s_setprio(1);
#pragma unroll
    for (int i = 0; i < 4; ++i)
#pragma unroll
      for (int j = 0; j < 2; ++j)
#pragma unroll
        for (int kk = 0; kk < 2; ++kk)
          ac[i][j] = __builtin_amdgcn_mfma_f32_16x16x32_bf16(af[i * 2 + kk], bfr[j * 2 + kk],
                                                             ac[i][j], 0, 0, 0);
    __builtin_amdgcn_s_setprio(0);
  };
  auto bar = [&]() {
    asm volatile("" ::: "memory");
    __builtin_amdgcn_s_barrier();
    asm volatile("" ::: "memory");
  };

  // prologue: tile0 -> buf0 (8 loads), tile1 -> buf1 (8 loads); drain tile0 before p1
  stage(0, 0, 0, 0); stage(1, 0, 0, 0); stage(0, 1, 0, 0); stage(1, 1, 0, 0);
  stage(1, 0, 1, 1); stage(0, 1, 1, 1); stage(1, 1, 1, 1); stage(0, 0, 1, 1);
  WAITV(8);
  bar();

  for (int i = 0; i < NP; ++i) {
    const bool stg = (i < NP - 1);
    const int t2 = 2 * i + 2, t3 = 2 * i + 3;
    // p1: q(0,0) on buf0
    lda(0, 0); ldb(0, 0);
    if (i > 0) stage(0, 0, 2 * i + 1, 1);
    bar();
    mf(acc[0][0]);
    // p2: q(1,0)
    lda(1, 0);
    if (stg) stage(1, 0, t2, 0);
    bar();
    mf(acc[1][0]);
    // p3: q(1,1)
    ldb(1, 0);
    if (stg) stage(0, 1, t2, 0);
    bar();
    mf(acc[1][1]);
    // p4: q(0,1) — K-tile wait (counted)
    lda(0, 0);
    if (stg) { stage(1, 1, t2, 0); WAITV(4); } else { WAITV(0); }
    bar();
    mf(acc[0][1]);
    // p5: q(0,0) on buf1
    lda(0, 1); ldb(0, 1);
    if (stg) stage(0, 0, t2, 0);
    bar();
    mf(acc[0][0]);
    // p6: q(1,0)
    lda(1, 1);
    if (stg) stage(1, 0, t3, 1);
    bar();
    mf(acc[1][0]);
    // p7: q(1,1)
    ldb(1, 1);
    if (stg) stage(0, 1, t3, 1);
    bar();
    mf(acc[1][1]);
    // p8: q(0,1) — K-tile wait (counted)
    lda(0, 1);
    if (stg) { stage(1, 1, t3, 1); WAITV(4); }
    bar();
    mf(acc[0][1]);
  }

#pragma unroll
  for (int qa = 0; qa < 2; ++qa)
#pragma unroll
    for (int qb = 0; qb < 2; ++qb)
#pragma unroll
      for (int i = 0; i < 4; ++i)
#pragma unroll
        for (int j = 0; j < 2; ++j)
#pragma unroll
          for (int tt = 0; tt < 4; ++tt) {
            const int r = row0 + qa * 128 + wrow * 64 + i * 16 + (l >> 4) * 4 + tt;
            const int cc = col0 + qb * 128 + wcol * 32 + j * 16 + (l & 15);
            float v = acc[qa][qb][i][j][tt] + bias[cc];
            if (ACT == 1) v = fmaxf(v, 0.0f);
            if (ACT == 2) v = fabsf(v);
            if (ACT == 0)
              ((float*)Cp)[(size_t)r * N + cc] = v;
            else
              ((unsigned short*)Cp)[(size_t)r * N + cc] = f2bfu(v);
          }
}

// Per-row fusion: hidden = elu(sum_a q[a]*|w1[b,a,:]| + b1), q_tot = hidden.wf + vh.vw2 + vb2
__global__ void final_kernel(const float* __restrict__ qs, const unsigned short* __restrict__ w1c,
                             const float* __restrict__ b1, const unsigned short* __restrict__ wf,
                             const unsigned short* __restrict__ vh, const float* __restrict__ vw2,
                             const float* __restrict__ vb2, float* __restrict__ out, int row0) {
  const int tid = threadIdx.x;               // e in [0,256)
  const int b = row0 + blockIdx.x;
  const unsigned short* wrow = w1c + (size_t)blockIdx.x * (A_DIM * E_DIM);
  const float* qrow = qs + (size_t)b * A_DIM;
  float acc = b1[(size_t)b * E_DIM + tid];
#pragma unroll 8
  for (int a = 0; a < A_DIM; ++a)
    acc = fmaf(qrow[a], bf2f(wrow[a * E_DIM + tid]), acc);
  float hidden = acc > 0.0f ? acc : (expf(acc) - 1.0f);  // elu, alpha=1
  float s = hidden * bf2f(wf[(size_t)b * E_DIM + tid]) +
            bf2f(vh[(size_t)b * E_DIM + tid]) * vw2[tid];
  __shared__ float red[4];
#pragma unroll
  for (int o = 32; o > 0; o >>= 1) s += __shfl_down(s, o, 64);
  if ((tid & 63) == 0) red[tid >> 6] = s;
  __syncthreads();
  if (tid == 0) out[b] = red[0] + red[1] + red[2] + red[3] + vb2[0];
}

extern "C" void kernel_launch(void* const* d_in, const int* in_sizes, int n_in,
                              void* d_out, int out_size, void* d_ws, size_t ws_size,
                              hipStream_t stream) {
  const float* agent_qs = (const float*)d_in[0];
  const float* states = (const float*)d_in[1];
  const float* hw1_w1 = (const float*)d_in[2];
  const float* hw1_b1 = (const float*)d_in[3];
  const float* hw1_w2 = (const float*)d_in[4];
  const float* hw1_b2 = (const float*)d_in[5];
  const float* hb1_w = (const float*)d_in[6];
  const float* hb1_b = (const float*)d_in[7];
  const float* hwf_w1 = (const float*)d_in[8];
  const float* hwf_b1 = (const float*)d_in[9];
  const float* hwf_w2 = (const float*)d_in[10];
  const float* hwf_b2 = (const float*)d_in[11];
  const float* v_w1 = (const float*)d_in[12];
  const float* v_b1 = (const float*)d_in[13];
  const float* v_w2 = (const float*)d_in[14];
  const float* v_b2 = (const float*)d_in[15];
  float* out = (float*)d_out;

  size_t off = 0;
  char* ws = (char*)d_ws;
  auto carve = [&](size_t bytes) -> void* {
    void* p = ws + off;
    off = (off + bytes + 255) & ~(size_t)255;
    return p;
  };
  unsigned short* st_bf = (unsigned short*)carve((size_t)B_SZ * S_DIM * 2);
  unsigned short* w11T = (unsigned short*)carve((size_t)H_DIM * S_DIM * 2);
  unsigned short* w12T = (unsigned short*)carve((size_t)8192 * H_DIM * 2);
  unsigned short* wb1T = (unsigned short*)carve((size_t)E_DIM * S_DIM * 2);
  unsigned short* wf1T = (unsigned short*)carve((size_t)H_DIM * S_DIM * 2);
  unsigned short* wf2T = (unsigned short*)carve((size_t)E_DIM * H_DIM * 2);
  unsigned short* wv1T = (unsigned short*)carve((size_t)E_DIM * S_DIM * 2);
  unsigned short* h1 = (unsigned short*)carve((size_t)B_SZ * H_DIM * 2);
  unsigned short* hfb = (unsigned short*)carve((size_t)B_SZ * H_DIM * 2);
  float* b1f = (float*)carve((size_t)B_SZ * E_DIM * 4);
  unsigned short* wfb = (unsigned short*)carve((size_t)B_SZ * E_DIM * 2);
  unsigned short* vhb = (unsigned short*)carve((size_t)B_SZ * E_DIM * 2);
  size_t rem = (ws_size > off) ? ws_size - off : 0;
  int chunk = (int)(rem / ((size_t)8192 * 2));
  chunk &= ~255;
  if (chunk < 256) chunk = 256;
  if (chunk > B_SZ) chunk = B_SZ;
  unsigned short* w1c = (unsigned short*)(ws + off);

  // dtype converts (+ weight transposes to B^T layout)
  conv_kernel<<<(B_SZ * S_DIM / 4 + 255) / 256, 256, 0, stream>>>(states, st_bf, B_SZ * S_DIM);
  dim3 tb(32, 8);
  tconv_kernel<<<dim3(H_DIM / 32, S_DIM / 32), tb, 0, stream>>>(hw1_w1, w11T, S_DIM, H_DIM);
  tconv_kernel<<<dim3(8192 / 32, H_DIM / 32), tb, 0, stream>>>(hw1_w2, w12T, H_DIM, 8192);
  tconv_kernel<<<dim3(E_DIM / 32, S_DIM / 32), tb, 0, stream>>>(hb1_w, wb1T, S_DIM, E_DIM);
  tconv_kernel<<<dim3(H_DIM / 32, S_DIM / 32), tb, 0, stream>>>(hwf_w1, wf1T, S_DIM, H_DIM);
  tconv_kernel<<<dim3(E_DIM / 32, H_DIM / 32), tb, 0, stream>>>(hwf_w2, wf2T, H_DIM, E_DIM);
  tconv_kernel<<<dim3(E_DIM / 32, S_DIM / 32), tb, 0, stream>>>(v_w1, wv1T, S_DIM, E_DIM);

  // small/medium GEMMs (128-tile 2-phase structure)
  gemm_bt<1><<<dim3(H_DIM / 128, B_SZ / 128), 256, 0, stream>>>(st_bf, w11T, hw1_b1, h1, B_SZ, H_DIM, S_DIM);
  gemm_bt<1><<<dim3(H_DIM / 128, B_SZ / 128), 256, 0, stream>>>(st_bf, wf1T, hwf_b1, hfb, B_SZ, H_DIM, S_DIM);
  gemm_bt<0><<<dim3(E_DIM / 128, B_SZ / 128), 256, 0, stream>>>(st_bf, wb1T, hb1_b, b1f, B_SZ, E_DIM, S_DIM);
  gemm_bt<1><<<dim3(E_DIM / 128, B_SZ / 128), 256, 0, stream>>>(st_bf, wv1T, v_b1, vhb, B_SZ, E_DIM, S_DIM);
  gemm_bt<2><<<dim3(E_DIM / 128, B_SZ / 128), 256, 0, stream>>>(hfb, wf2T, hwf_b2, wfb, B_SZ, E_DIM, H_DIM);

  // big GEMM (w1) on the 256-tile 8-phase pipeline, in row-chunks + fused epilogue
  for (int row0 = 0; row0 < B_SZ; row0 += chunk) {
    int cm = chunk;
    if (row0 + cm > B_SZ) cm = B_SZ - row0;
    gemm256_bt<2><<<dim3(8192 / 256, cm / 256), 512, 0, stream>>>(
        h1 + (size_t)row0 * H_DIM, w12T, hw1_b2, w1c, cm, 8192, H_DIM);
    final_kernel<<<cm, 256, 0, stream>>>(agent_qs, w1c, b1f, wfb, vhb, v_w2, v_b2, out, row0);
  }
}